// Round 5
// baseline (284.086 us; speedup 1.0000x reference)
//
#include <hip/hip_runtime.h>

// B=8, C=64, D=8 (q/k), H=W=128.  dwconv3x3 -> CCA -> CCA -> pointwise.
// All intermediate tensors bf16 (y, z, AT, O); fp32 accum everywhere.
// MFMA flash CCA (ccdir); transposes fused into producers (dwconv writes
// y+yT; combineT writes Bo+BoT). LDS 31744 B in ccdir -> 5 blocks/CU.
// Staging layout ys[p][c] uses XOR swizzle c^=(p&7)<<3 (8-granular, keeps
// bf8 fragments contiguous) to cut LDS bank conflicts.
// Fragment layouts (mfma_f32_16x16x32_bf16):
//   A[m=lane&15][k=quad*8+j (+32s)], B[k][n=lane&15], C col=lane&15,row=quad*4+reg

#define NEGINF -3.0e38f
#define YSTR 64
#define VSTR 72
#define PSTR 72

typedef __attribute__((ext_vector_type(8))) __bf16 bf8;
typedef __attribute__((ext_vector_type(4))) float f4;

__device__ __forceinline__ f4 MFMA(bf8 a, bf8 b, f4 c) {
  return __builtin_amdgcn_mfma_f32_16x16x32_bf16(a, b, c, 0, 0, 0);
}
__device__ __forceinline__ ushort bfb(float f) {
  __bf16 h = (__bf16)f;
  return *(ushort*)&h;
}

// 32x32-tile dwconv3x3; writes y and yT (bf16), packed ushort2 stores.
__global__ __launch_bounds__(256) void dwconv_kernel(
    const float* __restrict__ x, const float* __restrict__ wdw,
    __bf16* __restrict__ y, __bf16* __restrict__ yT) {
  __shared__ float in[34][36];
  __shared__ float ot[32][33];
  int tx = threadIdx.x & 31, ty = threadIdx.x >> 5;   // 32x8
  int w0 = blockIdx.x*32, h0 = blockIdx.y*32;
  int n = blockIdx.z;                                  // b*64 + c
  const float* xp = x + (size_t)n*16384;
  const float* wp = wdw + (n & 63)*9;
  float wr[9];
  #pragma unroll
  for (int j = 0; j < 9; ++j) wr[j] = wp[j];
  for (int i = ty; i < 34; i += 8) {
    int hh = h0 + i - 1;
    for (int j = tx; j < 34; j += 32) {
      int ww = w0 + j - 1;
      float v = 0.f;
      if (hh >= 0 && hh < 128 && ww >= 0 && ww < 128) v = xp[hh*128 + ww];
      in[i][j] = v;
    }
  }
  __syncthreads();
  for (int i2 = ty; i2 < 32; i2 += 8) {
    float acc = 0.f;
    #pragma unroll
    for (int kh = 0; kh < 3; ++kh)
      #pragma unroll
      for (int kw = 0; kw < 3; ++kw)
        acc += wr[kh*3 + kw]*in[i2 + kh][tx + kw];
    ot[i2][tx] = acc;
  }
  __syncthreads();
  ushort* yp  = (ushort*)(y  + (size_t)n*16384);
  ushort* ytp = (ushort*)(yT + (size_t)n*16384);
  for (int idx = threadIdx.x; idx < 512; idx += 256) {
    int row = idx >> 4, c2 = (idx & 15)*2;
    ushort2 u;
    u.x = bfb(ot[row][c2]); u.y = bfb(ot[row][c2 + 1]);
    *(ushort2*)&yp[(size_t)(h0 + row)*128 + w0 + c2] = u;
    ushort2 v;
    v.x = bfb(ot[c2][row]); v.y = bfb(ot[c2 + 1][row]);
    *(ushort2*)&ytp[(size_t)(w0 + row)*128 + h0 + c2] = v;
  }
}

// Fused CCA direction kernel. dir=0: src=A row pass -> dstRow, stats mW,sW.
// dir=1: src=dst=AT (in place), diag mask, stats mH,sH.
// Output O UNNORMALIZED bf16: O[d][p] = sum_c exp(e(p,c)-m[p]) * v[d][c].
__global__ __launch_bounds__(256) void ccdir_kernel(
    const __bf16* __restrict__ srcRow, __bf16* __restrict__ dstRow,
    __bf16* __restrict__ srcdstCol,
    const float* __restrict__ wq, const float* __restrict__ wk,
    const float* __restrict__ wv,
    float* __restrict__ mW, float* __restrict__ sW,
    float* __restrict__ mH, float* __restrict__ sH) {
  // LDS bytes: vs[64][72]bf16 @0 (9216); ps[128][72]bf16 @9216 (18432;
  // aliases ys[128][64]bf16 and per-wave bf16 out-stage [64][34]);
  // qs[128][8]bf16 @27648; ks @29696.  Total 31744.
  __shared__ __align__(16) char smem[31744];
  __bf16* vs = (__bf16*)smem;
  __bf16* ps = (__bf16*)(smem + 9216);
  __bf16* ys = (__bf16*)(smem + 9216);
  __bf16* qs = (__bf16*)(smem + 27648);
  __bf16* ks = (__bf16*)(smem + 29696);

  int t = threadIdx.x;
  int r = blockIdx.x, b = blockIdx.y, dir = blockIdx.z;
  const __bf16* src = dir ? srcdstCol : srcRow;
  __bf16* dst       = dir ? srcdstCol : dstRow;
  float* mo         = dir ? mH : mW;
  float* so         = dir ? sH : sW;
  const ushort* sp = (const ushort*)(src + (size_t)b*1048576 + (size_t)r*128);

  // ---- phase 0: stage Y[c][p] -> ys[p][c^swz] (bf16 raw moves) ----
  for (int i = t; i < 4096; i += 256) {
    int p = i & 127, c = (i >> 7)*2;
    ushort u0 = sp[(size_t)c*16384 + p];
    ushort u1 = sp[(size_t)(c + 1)*16384 + p];
    int cs = c ^ ((p & 7) << 3);
    ushort2 uv; uv.x = u0; uv.y = u1;
    *(ushort2*)((ushort*)ys + p*YSTR + cs) = uv;
  }
  int lane = t & 63, w = t >> 6;
  int l16 = lane & 15, quad = lane >> 4;

  bf8 a_qk[2], a_wv[4][2];
  {
    const float* wr = (l16 < 8) ? (wq + l16*64) : (wk + (l16 - 8)*64);
    #pragma unroll
    for (int s = 0; s < 2; ++s) {
      int c0 = quad*8 + s*32;
      bf8 f;
      #pragma unroll
      for (int j = 0; j < 8; ++j) f[j] = (__bf16)wr[c0 + j];
      a_qk[s] = f;
    }
    #pragma unroll
    for (int m0 = 0; m0 < 4; ++m0) {
      const float* vr = wv + (m0*16 + l16)*64;
      #pragma unroll
      for (int s = 0; s < 2; ++s) {
        int c0 = quad*8 + s*32;
        bf8 f;
        #pragma unroll
        for (int j = 0; j < 8; ++j) f[j] = (__bf16)vr[c0 + j];
        a_wv[m0][s] = f;
      }
    }
  }
  __syncthreads();                      // ys staged

  // ---- phase 1: projections (wave owns p-block [32w, 32w+32)) ----
  f4 z4 = {0.f, 0.f, 0.f, 0.f};
  bf8 b_ys[2][2];
  #pragma unroll
  for (int nt = 0; nt < 2; ++nt) {
    int p = w*32 + nt*16 + l16;
    #pragma unroll
    for (int s = 0; s < 2; ++s)
      b_ys[nt][s] = *(const bf8*)&ys[p*YSTR + ((s*32 + quad*8) ^ ((p & 7) << 3))];
  }
  #pragma unroll
  for (int nt = 0; nt < 2; ++nt) {
    int p = w*32 + nt*16 + l16;
    f4 aqk = z4;
    aqk = MFMA(a_qk[0], b_ys[nt][0], aqk);
    aqk = MFMA(a_qk[1], b_ys[nt][1], aqk);
    __bf16* dp8 = ((quad < 2) ? qs : ks) + p*8 + (quad & 1)*4;
    #pragma unroll
    for (int rg = 0; rg < 4; ++rg) dp8[rg] = (__bf16)aqk[rg];
  }
  #pragma unroll
  for (int m0 = 0; m0 < 4; ++m0)
    #pragma unroll
    for (int nt = 0; nt < 2; ++nt) {
      f4 va = z4;
      va = MFMA(a_wv[m0][0], b_ys[nt][0], va);
      va = MFMA(a_wv[m0][1], b_ys[nt][1], va);
      int u = w*32 + nt*16 + l16;
      #pragma unroll
      for (int rg = 0; rg < 4; ++rg)
        vs[(m0*16 + quad*4 + rg)*VSTR + u] = (__bf16)va[rg];
    }
  __syncthreads();                      // qs/ks/vs visible; ys dead

  // ---- phase 2: E = Q^T K (K=8 via quad-0 lanes, others zero) ----
  bf8 zb;
  #pragma unroll
  for (int j = 0; j < 8; ++j) zb[j] = (__bf16)0.f;
  f4 e[2][8];
  #pragma unroll
  for (int mt = 0; mt < 2; ++mt) {
    int p = w*32 + mt*16 + l16;
    bf8 aq = (quad == 0) ? *(const bf8*)&qs[p*8] : zb;
    #pragma unroll
    for (int nt = 0; nt < 8; ++nt) {
      bf8 bk = (quad == 0) ? *(const bf8*)&ks[(nt*16 + l16)*8] : zb;
      e[mt][nt] = MFMA(aq, bk, z4);
    }
  }
  __syncthreads();                      // qs/ks reads done (ps will clobber)

  // ---- phase 3: row softmax stats + P = exp(e - m) -> ps (bf16) ----
  int sb = (b*128 + r) << 7;
  #pragma unroll
  for (int mt = 0; mt < 2; ++mt) {
    if (dir) {                          // diag mask: c' == p
      #pragma unroll
      for (int nt = 0; nt < 8; ++nt)
        #pragma unroll
        for (int rg = 0; rg < 4; ++rg)
          if (nt == 2*w + mt && l16 == quad*4 + rg) e[mt][nt][rg] = NEGINF;
    }
    float mx[4], sm[4];
    #pragma unroll
    for (int rg = 0; rg < 4; ++rg) {
      float m2 = e[mt][0][rg];
      #pragma unroll
      for (int nt = 1; nt < 8; ++nt) m2 = fmaxf(m2, e[mt][nt][rg]);
      #pragma unroll
      for (int d2 = 1; d2 < 16; d2 <<= 1) m2 = fmaxf(m2, __shfl_xor(m2, d2, 64));
      mx[rg] = m2;
      sm[rg] = 0.f;
    }
    int prow = w*32 + mt*16 + quad*4;
    #pragma unroll
    for (int nt = 0; nt < 8; ++nt)
      #pragma unroll
      for (int rg = 0; rg < 4; ++rg) {
        float pv = __expf(e[mt][nt][rg] - mx[rg]);
        sm[rg] += pv;
        ps[(prow + rg)*PSTR + nt*16 + l16] = (__bf16)pv;
      }
    #pragma unroll
    for (int rg = 0; rg < 4; ++rg) {
      float s2 = sm[rg];
      #pragma unroll
      for (int d2 = 1; d2 < 16; d2 <<= 1) s2 += __shfl_xor(s2, d2, 64);
      if (l16 == 0) {
        mo[sb + prow + rg] = mx[rg];
        so[sb + prow + rg] = s2;
      }
    }
  }
  __syncthreads();                      // ps visible

  // ---- phase 4: O = V x P^T  (M=64 d, N=32 p per wave, K=128) ----
  f4 acc[4][2];
  #pragma unroll
  for (int m0 = 0; m0 < 4; ++m0)
    #pragma unroll
    for (int nt = 0; nt < 2; ++nt) acc[m0][nt] = z4;
  #pragma unroll
  for (int s = 0; s < 4; ++s) {
    bf8 af[4], bfr[2];
    #pragma unroll
    for (int m0 = 0; m0 < 4; ++m0)
      af[m0] = *(const bf8*)&vs[(m0*16 + l16)*VSTR + s*32 + quad*8];
    #pragma unroll
    for (int nt = 0; nt < 2; ++nt)
      bfr[nt] = *(const bf8*)&ps[(w*32 + nt*16 + l16)*PSTR + s*32 + quad*8];
    #pragma unroll
    for (int m0 = 0; m0 < 4; ++m0)
      #pragma unroll
      for (int nt = 0; nt < 2; ++nt)
        acc[m0][nt] = MFMA(af[m0], bfr[nt], acc[m0][nt]);
  }
  __syncthreads();                      // ps reads done; reuse as out-stage

  // ---- phase 5: bf16 out-stage [64][34] per wave, packed stores ----
  __bf16* oS = (__bf16*)(smem + 9216 + 4352*w);
  #pragma unroll
  for (int m0 = 0; m0 < 4; ++m0)
    #pragma unroll
    for (int nt = 0; nt < 2; ++nt)
      #pragma unroll
      for (int rg = 0; rg < 4; ++rg)
        oS[(m0*16 + quad*4 + rg)*34 + nt*16 + l16] = (__bf16)acc[m0][nt][rg];
  ushort* dp = (ushort*)(dst + (size_t)b*1048576 + (size_t)r*128 + w*32);
  ushort* oSu = (ushort*)oS;
  for (int i = lane; i < 1024; i += 64) {
    int d = i >> 4, pp = (i & 15)*2;
    *(ushort2*)&dp[(size_t)d*16384 + pp] = *(ushort2*)&oSu[d*34 + pp];
  }
}

// Merge row stats (b,h,w) and col stats (b,w,h) -> per-pixel factors cW,cH.
__global__ __launch_bounds__(256) void scale_kernel(
    const float* __restrict__ mW, const float* __restrict__ sW,
    const float* __restrict__ mH, const float* __restrict__ sH,
    float* __restrict__ cW, float* __restrict__ cH) {
  __shared__ float tm[32][33], ts[32][33];
  int b = blockIdx.z;
  int x0 = blockIdx.x*32, y0 = blockIdx.y*32;
  const float* mh = mH + b*16384;
  const float* sh = sH + b*16384;
  for (int i = threadIdx.y; i < 32; i += 8) {
    tm[i][threadIdx.x] = mh[(y0 + i)*128 + x0 + threadIdx.x];
    ts[i][threadIdx.x] = sh[(y0 + i)*128 + x0 + threadIdx.x];
  }
  __syncthreads();
  for (int i = threadIdx.y; i < 32; i += 8) {
    int h = x0 + i, w2 = y0 + threadIdx.x;
    int idx = b*16384 + h*128 + w2;
    float mw = mW[idx], sw = sW[idx];
    float mhv = tm[threadIdx.x][i], shv = ts[threadIdx.x][i];
    float M = fmaxf(mw, mhv);
    float ew = __expf(mw - M), eh = __expf(mhv - M);
    float inv = 1.0f / (sw*ew + shv*eh);
    cW[idx] = ew*inv;
    cH[idx] = eh*inv;
  }
}

// Bo = gamma*(Bo*cW + oT^T*cH) + A (all bf16, fp32 math); optionally BoT.
// BoT may alias oT (tile staged to LDS before overwrite).
__global__ __launch_bounds__(256) void combineT_kernel(
    __bf16* __restrict__ Bo, const __bf16* oT,
    const __bf16* __restrict__ A, const float* __restrict__ cW,
    const float* __restrict__ cH, const float* __restrict__ gamma,
    __bf16* BoT, int writeT) {
  __shared__ float tile[32][33];
  __shared__ float rt[32][33];
  int n = blockIdx.z;                       // b*64 + d
  int b = n >> 6;
  int x0 = blockIdx.x*32, y0 = blockIdx.y*32;
  const __bf16* ip = oT + (size_t)n*16384;
  for (int i = threadIdx.y; i < 32; i += 8)
    tile[i][threadIdx.x] = (float)ip[(size_t)(y0 + i)*128 + x0 + threadIdx.x];
  __syncthreads();
  float g = *gamma;
  for (int i = threadIdx.y; i < 32; i += 8) {
    int h = x0 + i, w2 = y0 + threadIdx.x;
    size_t idx = (size_t)n*16384 + (size_t)h*128 + w2;
    int pix = b*16384 + h*128 + w2;
    float res = g*((float)Bo[idx]*cW[pix] + tile[threadIdx.x][i]*cH[pix])
                + (float)A[idx];
    Bo[idx] = (__bf16)res;
    rt[i][threadIdx.x] = res;               // value at (h=x0+i, w=y0+tx)
  }
  if (writeT) {
    __syncthreads();
    for (int i = threadIdx.y; i < 32; i += 8)
      BoT[(size_t)n*16384 + (size_t)(y0 + i)*128 + x0 + threadIdx.x] =
          (__bf16)rt[threadIdx.x][i];
  }
}

// MFMA pointwise 64->64 per (b,r) slice: out[o][p] = sum_c wpw[o][c]*A[c][p].
__global__ __launch_bounds__(256) void pw_kernel(
    const __bf16* __restrict__ A, const float* __restrict__ wpw,
    float* __restrict__ out) {
  // ys[128][64]bf16 @0 (16384); fp32 out-stage [64][33] per wave @8448*w
  // (aliases ys; total 33792).
  __shared__ __align__(16) char smem[33792];
  __bf16* ys = (__bf16*)smem;
  int t = threadIdx.x;
  int r = blockIdx.x, b = blockIdx.y;
  const ushort* sp = (const ushort*)(A + (size_t)b*1048576 + (size_t)r*128);
  for (int i = t; i < 4096; i += 256) {
    int p = i & 127, c = (i >> 7)*2;
    ushort u0 = sp[(size_t)c*16384 + p];
    ushort u1 = sp[(size_t)(c + 1)*16384 + p];
    int cs = c ^ ((p & 7) << 3);
    ushort2 uv; uv.x = u0; uv.y = u1;
    *(ushort2*)((ushort*)ys + p*YSTR + cs) = uv;
  }
  int lane = t & 63, w = t >> 6;
  int l16 = lane & 15, quad = lane >> 4;
  bf8 a_w[4][2];
  #pragma unroll
  for (int m0 = 0; m0 < 4; ++m0) {
    const float* wr = wpw + (m0*16 + l16)*64;
    #pragma unroll
    for (int s = 0; s < 2; ++s) {
      bf8 f;
      #pragma unroll
      for (int j = 0; j < 8; ++j) f[j] = (__bf16)wr[quad*8 + s*32 + j];
      a_w[m0][s] = f;
    }
  }
  __syncthreads();                     // ys staged
  bf8 b_ys[2][2];
  #pragma unroll
  for (int nt = 0; nt < 2; ++nt) {
    int p = w*32 + nt*16 + l16;
    #pragma unroll
    for (int s = 0; s < 2; ++s)
      b_ys[nt][s] = *(const bf8*)&ys[p*YSTR + ((s*32 + quad*8) ^ ((p & 7) << 3))];
  }
  __syncthreads();                     // all frag loads done; ys dead
  f4 z4 = {0.f, 0.f, 0.f, 0.f};
  f4 acc[4][2];
  #pragma unroll
  for (int m0 = 0; m0 < 4; ++m0)
    #pragma unroll
    for (int nt = 0; nt < 2; ++nt) {
      f4 a2 = z4;
      a2 = MFMA(a_w[m0][0], b_ys[nt][0], a2);
      a2 = MFMA(a_w[m0][1], b_ys[nt][1], a2);
      acc[m0][nt] = a2;
    }
  float* oS = (float*)(smem + 8448*w);  // [64][33] fp32, wave-local
  #pragma unroll
  for (int m0 = 0; m0 < 4; ++m0)
    #pragma unroll
    for (int nt = 0; nt < 2; ++nt)
      #pragma unroll
      for (int rg = 0; rg < 4; ++rg)
        oS[(m0*16 + quad*4 + rg)*33 + nt*16 + l16] = acc[m0][nt][rg];
  float* dp = out + (size_t)b*1048576 + (size_t)r*128 + w*32;
  for (int i = lane; i < 2048; i += 64) {
    int d = i >> 5, pp = i & 31;
    dp[(size_t)d*16384 + pp] = oS[d*33 + pp];
  }
}

extern "C" void kernel_launch(void* const* d_in, const int* in_sizes, int n_in,
                              void* d_out, int out_size, void* d_ws, size_t ws_size,
                              hipStream_t stream) {
  const float* x     = (const float*)d_in[0];
  const float* wdw   = (const float*)d_in[1];
  const float* wq    = (const float*)d_in[2];
  const float* wk    = (const float*)d_in[3];
  const float* wv    = (const float*)d_in[4];
  const float* gamma = (const float*)d_in[5];
  const float* wpw   = (const float*)d_in[6];
  float* out = (float*)d_out;

  // Workspace: 3 bf16 tensors (16 MB each) + 6 fp32 stat planes = 51 MB
  __bf16* y  = (__bf16*)d_ws;
  __bf16* z  = y + 8388608;
  __bf16* AT = z + 8388608;
  float* mW = (float*)(AT + 8388608);
  float* sW = mW + 131072;
  float* mH = sW + 131072;
  float* sH = mH + 131072;
  float* cW = sH + 131072;
  float* cH = cW + 131072;
  size_t need = (size_t)3*8388608*2 + (size_t)6*131072*4;
  if (ws_size < need) return;

  dwconv_kernel<<<dim3(4, 4, 512), 256, 0, stream>>>(x, wdw, y, AT);

  for (int pass = 0; pass < 2; ++pass) {
    const __bf16* A = pass ? z : y;   // CCA input / residual
    __bf16* Bo      = pass ? y : z;   // CCA output

    ccdir_kernel<<<dim3(128, 8, 2), 256, 0, stream>>>(
        A, Bo, AT, wq, wk, wv, mW, sW, mH, sH);
    scale_kernel<<<dim3(4, 4, 8), dim3(32, 8), 0, stream>>>(mW, sW, mH, sH, cW, cH);
    // pass 0: also write Bo^T into AT (becomes next pass's transposed input)
    combineT_kernel<<<dim3(4, 4, 512), dim3(32, 8), 0, stream>>>(
        Bo, AT, A, cW, cH, gamma, AT, pass == 0 ? 1 : 0);
  }

  pw_kernel<<<dim3(128, 8), 256, 0, stream>>>(y, wpw, out);
}